// Round 1
// baseline (342.727 us; speedup 1.0000x reference)
//
#include <hip/hip_runtime.h>
#include <hip/hip_bf16.h>

// Problem: B=4, T=2048, DIM=1024, H=16, DH=64.  fp32 in/out, bf16 MFMA inside.
// qkv col o = d*48 + kk*16 + h (d outermost, h innermost).

typedef __attribute__((ext_vector_type(8))) short short8;
typedef __attribute__((ext_vector_type(4))) float floatx4;

static __device__ __forceinline__ floatx4 mfma16(short8 a, short8 b, floatx4 c) {
    return __builtin_amdgcn_mfma_f32_16x16x32_bf16(a, b, c, 0, 0, 0);
}

static __device__ __forceinline__ unsigned short f2bf_bits(float f) {
    __hip_bfloat16 h = __float2bfloat16(f);
    return *reinterpret_cast<unsigned short*>(&h);
}

static __device__ __forceinline__ float fast_exp2(float x) {
#if __has_builtin(__builtin_amdgcn_exp2f)
    return __builtin_amdgcn_exp2f(x);
#else
    return exp2f(x);
#endif
}

// async global->LDS, 16 B per lane; LDS dest = wave-uniform base + lane*16
#define GLD16(gptr, ldsptr)                                                  \
    __builtin_amdgcn_global_load_lds(                                        \
        (const __attribute__((address_space(1))) void*)(gptr),               \
        (__attribute__((address_space(3))) void*)(ldsptr), 16, 0, 0)

// ---------------------------------------------------------------------------
// Kernel 0: fp32 -> bf16 conversion
// ---------------------------------------------------------------------------
__global__ __launch_bounds__(256) void k_cvt(
    const float* __restrict__ src, unsigned short* __restrict__ dst, int n4)
{
    typedef __attribute__((ext_vector_type(4))) unsigned short ushort4v;
    for (int i = blockIdx.x * blockDim.x + threadIdx.x; i < n4;
         i += gridDim.x * blockDim.x) {
        const float4 v = ((const float4*)src)[i];
        ushort4v o;
        o.x = f2bf_bits(v.x);
        o.y = f2bf_bits(v.y);
        o.z = f2bf_bits(v.z);
        o.w = f2bf_bits(v.w);
        ((ushort4v*)dst)[i] = o;
    }
}

// ---------------------------------------------------------------------------
// Kernel 1: QKV projection, m97-style global_load_lds staging.
// NEW: for Q/K the block's 128 B-columns map to (64 d x 2 h) and an LDS
// transpose epilogue writes [bh][t][d] directly (kills the k_tr kernels and
// makes stores full 128B lines).  V keeps the (8 d x 16 h) mapping and the
// [bh][d][t] layout.  q pre-scaled by log2(e)/32.
// ---------------------------------------------------------------------------
__global__ __launch_bounds__(256) void k_qkv(
    const unsigned short* __restrict__ x,   // [8192][1024] bf16
    const unsigned short* __restrict__ wq,  // [3072][1024] bf16
    unsigned short* __restrict__ qb,        // [64 bh][2048 t][64 d]
    unsigned short* __restrict__ kb,        // [64 bh][2048 t][64 d]
    unsigned short* __restrict__ vb)        // [64 bh][64 d][2048 t]
{
    // union region: K-loop uses [0,4096) = As, [4096,8192) = Bs;
    // Q/K epilogue reuses [0,9216) as T[128][72] (one h-slab at a time).
    __shared__ unsigned short SM[9216];

    const int tid  = threadIdx.x;
    const int wave = tid >> 6, lane = tid & 63;
    const int quad = lane >> 4, l16 = lane & 15;
    const int wm = wave >> 1, wn = wave & 1;
    const int m0 = blockIdx.y * 128;
    const int kk = blockIdx.x >> 3;
    const int cb = blockIdx.x & 7;

    // staging: wave w covers rows w*32 .. w*32+31 in two 16-row chunks
    const int srow = lane >> 2;          // 0..15
    const int sc8  = (lane & 3) * 8;     // 0,8,16,24
    const int row0 = wave * 32 + srow;
    const int row1 = row0 + 16;
    int bn0, bn1;
    if (kk < 2) {
        // column n -> d = n&63, h = cb*2 + (n>>6)
        bn0 = (row0 & 63) * 48 + kk * 16 + cb * 2 + (row0 >> 6);
        bn1 = (row1 & 63) * 48 + kk * 16 + cb * 2 + (row1 >> 6);
    } else {
        // column n -> d = cb*8 + (n>>4), h = n&15  (original mapping)
        bn0 = (cb * 8 + (row0 >> 4)) * 48 + 32 + (row0 & 15);
        bn1 = (cb * 8 + (row1 >> 4)) * 48 + 32 + (row1 & 15);
    }

    floatx4 acc[4][4];
#pragma unroll
    for (int i = 0; i < 4; i++)
#pragma unroll
        for (int j = 0; j < 4; j++) acc[i][j] = (floatx4){0.f, 0.f, 0.f, 0.f};

    for (int k0 = 0; k0 < 1024; k0 += 32) {
        GLD16(&x[(m0 + row0) * 1024 + k0 + sc8], &SM[(wave * 32) * 32]);
        GLD16(&x[(m0 + row1) * 1024 + k0 + sc8], &SM[(wave * 32 + 16) * 32]);
        GLD16(&wq[bn0 * 1024 + k0 + sc8],        &SM[4096 + (wave * 32) * 32]);
        GLD16(&wq[bn1 * 1024 + k0 + sc8],        &SM[4096 + (wave * 32 + 16) * 32]);
        __syncthreads();

        short8 af[4], bfv[4];
#pragma unroll
        for (int mi = 0; mi < 4; mi++)
            af[mi] = *(const short8*)&SM[(wm * 64 + mi * 16 + l16) * 32 + quad * 8];
#pragma unroll
        for (int ni = 0; ni < 4; ni++)
            bfv[ni] = *(const short8*)&SM[4096 + (wn * 64 + ni * 16 + l16) * 32 + quad * 8];
#pragma unroll
        for (int mi = 0; mi < 4; mi++)
#pragma unroll
            for (int ni = 0; ni < 4; ni++)
                acc[mi][ni] = mfma16(af[mi], bfv[ni], acc[mi][ni]);
        __syncthreads();
    }

    if (kk == 2) {
        // V epilogue: [bh][d][t], packed ushort4 along t (unchanged)
#pragma unroll
        for (int ni = 0; ni < 4; ni++) {
            const int d = cb * 8 + wn * 4 + ni;
#pragma unroll
            for (int mi = 0; mi < 4; mi++) {
                const int m  = m0 + wm * 64 + mi * 16 + quad * 4;
                const int b  = m >> 11;
                const int tt = m & 2047;
                ushort4 pk;
                pk.x = f2bf_bits(acc[mi][ni][0]);
                pk.y = f2bf_bits(acc[mi][ni][1]);
                pk.z = f2bf_bits(acc[mi][ni][2]);
                pk.w = f2bf_bits(acc[mi][ni][3]);
                *(ushort4*)&vb[((b * 16 + l16) * 64 + d) * 2048 + tt] = pk;
            }
        }
    } else {
        // Q/K epilogue: LDS transpose to [bh][t][d], one h-slab per pass.
        const float scale = (kk == 0) ? 0.045084220027780106f : 1.0f;  // log2(e)/32
        unsigned short* dst = (kk == 0) ? qb : kb;
        const int b = m0 >> 11, tt0 = m0 & 2047;   // block lies in one batch
#pragma unroll
        for (int s = 0; s < 2; s++) {
            if (wn == s) {  // waves s and s+2 own this h-slab (wm = 0,1)
#pragma unroll
                for (int ni = 0; ni < 4; ni++) {
                    const int d = ni * 16 + l16;
#pragma unroll
                    for (int mi = 0; mi < 4; mi++) {
                        const int tl = wm * 64 + mi * 16 + quad * 4;
#pragma unroll
                        for (int r = 0; r < 4; r++)
                            SM[(tl + r) * 72 + d] = f2bf_bits(acc[mi][ni][r] * scale);
                    }
                }
            }
            __syncthreads();
            // coalesced read-back: full 128B t-rows
#pragma unroll
            for (int u = 0; u < 4; u++) {
                const int w  = tid + u * 256;     // 0..1023
                const int tl = w >> 3;
                const int ch = (w & 7) * 8;
                *(uint4*)&dst[((b * 16 + cb * 2 + s) * 2048 + tt0 + tl) * 64 + ch] =
                    *(const uint4*)&SM[tl * 72 + ch];
            }
            __syncthreads();
        }
    }
}

// ---------------------------------------------------------------------------
// Kernel 2: flash attention, 512-thread / 8-wave blocks, Q-tile 256 rows.
// NEW: KV staged 128 keys per barrier round (halves barrier count) and
// async-stage split (T14): next tile's K/V loaded to registers right after
// the barrier, ds_written at the top of the next round -> HBM/L2 latency
// hides under ~2 rounds of MFMA+softmax.  setprio(1) wraps MFMA clusters.
// ---------------------------------------------------------------------------
__global__ __launch_bounds__(512) void k_attn(
    const unsigned short* __restrict__ qt,  // [64][2048][64]  (bh, t, d)
    const unsigned short* __restrict__ kt,  // [64][2048][64]
    const unsigned short* __restrict__ vg,  // [64][64][2048]  (bh, d, t)
    __hip_bfloat16* __restrict__ og)        // [4][2048][1024]
{
    __shared__ unsigned short Ks[128 * 72];     // [key][d]       18432 B
    __shared__ unsigned short Vt[64 * 136];     // [d][key]       17408 B
    __shared__ unsigned short Pt[8 * 32 * 72];  // [qrow][key]    36864 B   (72704 total, 2 blk/CU)

    const int tid  = threadIdx.x;
    const int wave = tid >> 6, lane = tid & 63;
    const int quad = lane >> 4, l16 = lane & 15;
    const int blk = blockIdx.x;
    const int bh  = (blk & 7) | ((blk >> 6) << 3);  // XCD-affine
    const int q0  = ((blk >> 3) & 7) * 256;
    const int qr  = q0 + wave * 32;

    // Q fragments direct from global (used as B operand)
    short8 qf[2][2];
#pragma unroll
    for (int mi = 0; mi < 2; mi++)
#pragma unroll
        for (int ks = 0; ks < 2; ks++)
            qf[mi][ks] = *(const short8*)&qt[(bh * 2048 + qr + mi * 16 + l16) * 64 + ks * 32 + quad * 8];

    float lsum[2] = {0.f, 0.f};
    floatx4 o[2][4];
#pragma unroll
    for (int mi = 0; mi < 2; mi++)
#pragma unroll
        for (int di = 0; di < 4; di++) o[mi][di] = (floatx4){0.f, 0.f, 0.f, 0.f};

    // staging decomposition: 512 threads x 2 units cover 128x64 (K) / 64x128 (V)
    const int kr = tid >> 3, kc = (tid & 7) * 8;    // K rows kr, kr+64
    const int vd = tid >> 4, vc = (tid & 15) * 8;   // V d-rows vd, vd+32

    // T14 prefetch registers: first tile
    uint4 rk0 = *(const uint4*)&kt[(bh * 2048 + kr) * 64 + kc];
    uint4 rk1 = *(const uint4*)&kt[(bh * 2048 + 64 + kr) * 64 + kc];
    uint4 rv0 = *(const uint4*)&vg[(bh * 64 + vd) * 2048 + vc];
    uint4 rv1 = *(const uint4*)&vg[(bh * 64 + 32 + vd) * 2048 + vc];

    for (int j0 = 0; j0 < 2048; j0 += 128) {
        *(uint4*)&Ks[kr * 72 + kc]         = rk0;
        *(uint4*)&Ks[(64 + kr) * 72 + kc]  = rk1;
        *(uint4*)&Vt[vd * 136 + vc]        = rv0;
        *(uint4*)&Vt[(32 + vd) * 136 + vc] = rv1;
        __syncthreads();
        if (j0 + 128 < 2048) {  // issue next-tile loads; consumed at next top
            rk0 = *(const uint4*)&kt[(bh * 2048 + j0 + 128 + kr) * 64 + kc];
            rk1 = *(const uint4*)&kt[(bh * 2048 + j0 + 192 + kr) * 64 + kc];
            rv0 = *(const uint4*)&vg[(bh * 64 + vd) * 2048 + j0 + 128 + vc];
            rv1 = *(const uint4*)&vg[(bh * 64 + 32 + vd) * 2048 + j0 + 128 + vc];
        }

#pragma unroll
        for (int jj = 0; jj < 2; jj++) {
            const int kb0 = jj * 64;

            // S^T = K Q^T: D[m=key][n=qrow]
            floatx4 st[2][4];
#pragma unroll
            for (int mi = 0; mi < 2; mi++)
#pragma unroll
                for (int nk = 0; nk < 4; nk++) st[mi][nk] = (floatx4){0.f, 0.f, 0.f, 0.f};
#pragma unroll
            for (int ks = 0; ks < 2; ks++) {
                short8 kf[4];
#pragma unroll
                for (int nk = 0; nk < 4; nk++)
                    kf[nk] = *(const short8*)&Ks[(kb0 + nk * 16 + l16) * 72 + ks * 32 + quad * 8];
                __builtin_amdgcn_s_setprio(1);
#pragma unroll
                for (int mi = 0; mi < 2; mi++)
#pragma unroll
                    for (int nk = 0; nk < 4; nk++)
                        st[mi][nk] = mfma16(kf[nk], qf[mi][ks], st[mi][nk]);
                __builtin_amdgcn_s_setprio(0);
            }

            // p = 2^s; quartet = 4 consecutive keys at qrow=l16 -> packed write
#pragma unroll
            for (int mi = 0; mi < 2; mi++) {
#pragma unroll
                for (int nk = 0; nk < 4; nk++) {
                    const float p0 = fast_exp2(st[mi][nk][0]);
                    const float p1 = fast_exp2(st[mi][nk][1]);
                    const float p2 = fast_exp2(st[mi][nk][2]);
                    const float p3 = fast_exp2(st[mi][nk][3]);
                    lsum[mi] += (p0 + p1) + (p2 + p3);
                    ushort4 pk;
                    pk.x = f2bf_bits(p0);
                    pk.y = f2bf_bits(p1);
                    pk.z = f2bf_bits(p2);
                    pk.w = f2bf_bits(p3);
                    *(ushort4*)&Pt[(wave * 32 + mi * 16 + l16) * 72 + nk * 16 + quad * 4] = pk;
                }
            }
            __builtin_amdgcn_s_waitcnt(0xc07f);  // lgkmcnt(0): wave-local LDS RAW

            // O += P V
#pragma unroll
            for (int ks = 0; ks < 2; ks++) {
                short8 pf[2], vf[4];
#pragma unroll
                for (int mi = 0; mi < 2; mi++)
                    pf[mi] = *(const short8*)&Pt[(wave * 32 + mi * 16 + l16) * 72 + ks * 32 + quad * 8];
#pragma unroll
                for (int di = 0; di < 4; di++)
                    vf[di] = *(const short8*)&Vt[(di * 16 + l16) * 136 + kb0 + ks * 32 + quad * 8];
                __builtin_amdgcn_s_setprio(1);
#pragma unroll
                for (int mi = 0; mi < 2; mi++)
#pragma unroll
                    for (int di = 0; di < 4; di++)
                        o[mi][di] = mfma16(pf[mi], vf[di], o[mi][di]);
                __builtin_amdgcn_s_setprio(0);
            }
        }
        __syncthreads();
    }

    // reduce lsum across quads (keys were quad-partitioned)
#pragma unroll
    for (int mi = 0; mi < 2; mi++) {
        float t = lsum[mi];
        t += __shfl_xor(t, 16);
        t += __shfl_xor(t, 32);
        lsum[mi] = t;
    }

    // epilogue: o / l -> [b][t][h*64+d]
    const int b = bh >> 4, h = bh & 15;
#pragma unroll
    for (int mi = 0; mi < 2; mi++) {
#pragma unroll
        for (int r = 0; r < 4; r++) {
            const float inv = 1.0f / __shfl(lsum[mi], quad * 4 + r);
            const int t = qr + mi * 16 + quad * 4 + r;
#pragma unroll
            for (int di = 0; di < 4; di++)
                og[(b * 2048 + t) * 1024 + h * 64 + di * 16 + l16] =
                    __float2bfloat16(o[mi][di][r] * inv);
        }
    }
}

// ---------------------------------------------------------------------------
// Kernel 3: output projection, m97-style staging.  fp32 bias / fp32 out.
// ---------------------------------------------------------------------------
__global__ __launch_bounds__(256) void k_out(
    const unsigned short* __restrict__ a,    // [8192][1024] bf16
    const unsigned short* __restrict__ wq,   // [1024][1024] bf16
    const float* __restrict__ bias,
    float* __restrict__ out)                 // [8192][1024] fp32
{
    __shared__ unsigned short As[128 * 32];
    __shared__ unsigned short Bs[128 * 32];

    const int tid  = threadIdx.x;
    const int wave = tid >> 6, lane = tid & 63;
    const int quad = lane >> 4, l16 = lane & 15;
    const int wm = wave >> 1, wn = wave & 1;
    const int m0 = blockIdx.y * 128, n0 = blockIdx.x * 128;

    const int srow = lane >> 2;
    const int sc8  = (lane & 3) * 8;
    const int row0 = wave * 32 + srow;
    const int row1 = row0 + 16;

    floatx4 acc[4][4];
#pragma unroll
    for (int i = 0; i < 4; i++)
#pragma unroll
        for (int j = 0; j < 4; j++) acc[i][j] = (floatx4){0.f, 0.f, 0.f, 0.f};

    for (int k0 = 0; k0 < 1024; k0 += 32) {
        GLD16(&a[(m0 + row0) * 1024 + k0 + sc8],  &As[(wave * 32) * 32]);
        GLD16(&a[(m0 + row1) * 1024 + k0 + sc8],  &As[(wave * 32 + 16) * 32]);
        GLD16(&wq[(n0 + row0) * 1024 + k0 + sc8], &Bs[(wave * 32) * 32]);
        GLD16(&wq[(n0 + row1) * 1024 + k0 + sc8], &Bs[(wave * 32 + 16) * 32]);
        __syncthreads();

        short8 af[4], bfv[4];
#pragma unroll
        for (int mi = 0; mi < 4; mi++)
            af[mi] = *(const short8*)&As[(wm * 64 + mi * 16 + l16) * 32 + quad * 8];
#pragma unroll
        for (int ni = 0; ni < 4; ni++)
            bfv[ni] = *(const short8*)&Bs[(wn * 64 + ni * 16 + l16) * 32 + quad * 8];
#pragma unroll
        for (int mi = 0; mi < 4; mi++)
#pragma unroll
            for (int ni = 0; ni < 4; ni++)
                acc[mi][ni] = mfma16(af[mi], bfv[ni], acc[mi][ni]);
        __syncthreads();
    }

#pragma unroll
    for (int ni = 0; ni < 4; ni++) {
        const int col = n0 + wn * 64 + ni * 16 + l16;
        const float bv = bias[col];
#pragma unroll
        for (int mi = 0; mi < 4; mi++) {
            const int mbase = m0 + wm * 64 + mi * 16 + quad * 4;
#pragma unroll
            for (int r = 0; r < 4; r++)
                out[(mbase + r) * 1024 + col] = acc[mi][ni][r] + bv;
        }
    }
}

// ---------------------------------------------------------------------------
extern "C" void kernel_launch(void* const* d_in, const int* in_sizes, int n_in,
                              void* d_out, int out_size, void* d_ws, size_t ws_size,
                              hipStream_t stream) {
    const float* x    = (const float*)d_in[0];
    const float* wqkv = (const float*)d_in[1];
    const float* wout = (const float*)d_in[2];
    const float* bout = (const float*)d_in[3];
    float* out = (float*)d_out;

    unsigned short* ws = (unsigned short*)d_ws;
    unsigned short* xb    = ws;                  // x bf16
    unsigned short* wqkvb = xb + 8388608;
    unsigned short* woutb = wqkvb + 3145728;
    unsigned short* qb    = woutb + 1048576;     // q [bh][t][d] (direct)
    unsigned short* kb    = qb + 8388608;        // k [bh][t][d] (direct)
    unsigned short* vb    = kb + 8388608;        // v [bh][d][t]
    unsigned short* ob    = vb + 8388608;        // attn out

    k_cvt<<<2048, 256, 0, stream>>>(x,    xb,    8388608 / 4);
    k_cvt<<<1024, 256, 0, stream>>>(wqkv, wqkvb, 3145728 / 4);
    k_cvt<<<512,  256, 0, stream>>>(wout, woutb, 1048576 / 4);

    k_qkv<<<dim3(24, 64), 256, 0, stream>>>(xb, wqkvb, qb, kb, vb);
    k_attn<<<512, 512, 0, stream>>>(qb, kb, vb, (__hip_bfloat16*)ob);
    k_out<<<dim3(8, 64), 256, 0, stream>>>(ob, woutb, bout, out);
}

// Round 2
// 268.030 us; speedup vs baseline: 1.2787x; 1.2787x over previous
//
#include <hip/hip_runtime.h>
#include <hip/hip_bf16.h>

// Problem: B=4, T=2048, DIM=1024, H=16, DH=64.  fp32 in/out, bf16 MFMA inside.
// qkv col o = d*48 + kk*16 + h (d outermost, h innermost).

typedef __attribute__((ext_vector_type(8))) short short8;
typedef __attribute__((ext_vector_type(4))) float floatx4;

static __device__ __forceinline__ floatx4 mfma16(short8 a, short8 b, floatx4 c) {
    return __builtin_amdgcn_mfma_f32_16x16x32_bf16(a, b, c, 0, 0, 0);
}

static __device__ __forceinline__ unsigned short f2bf_bits(float f) {
    __hip_bfloat16 h = __float2bfloat16(f);
    return *reinterpret_cast<unsigned short*>(&h);
}

static __device__ __forceinline__ float fast_exp2(float x) {
#if __has_builtin(__builtin_amdgcn_exp2f)
    return __builtin_amdgcn_exp2f(x);
#else
    return exp2f(x);
#endif
}

// async global->LDS, 16 B per lane; LDS dest = wave-uniform base + lane*16
#define GLD16(gptr, ldsptr)                                                  \
    __builtin_amdgcn_global_load_lds(                                        \
        (const __attribute__((address_space(1))) void*)(gptr),               \
        (__attribute__((address_space(3))) void*)(ldsptr), 16, 0, 0)

// ---------------------------------------------------------------------------
// Kernel 0: fp32 -> bf16 conversion
// ---------------------------------------------------------------------------
__global__ __launch_bounds__(256) void k_cvt(
    const float* __restrict__ src, unsigned short* __restrict__ dst, int n4)
{
    typedef __attribute__((ext_vector_type(4))) unsigned short ushort4v;
    for (int i = blockIdx.x * blockDim.x + threadIdx.x; i < n4;
         i += gridDim.x * blockDim.x) {
        const float4 v = ((const float4*)src)[i];
        ushort4v o;
        o.x = f2bf_bits(v.x);
        o.y = f2bf_bits(v.y);
        o.z = f2bf_bits(v.z);
        o.w = f2bf_bits(v.w);
        ((ushort4v*)dst)[i] = o;
    }
}

// ---------------------------------------------------------------------------
// Kernel 1: QKV projection.  NEW this round:
//  * 2-phase double-buffered global_load_lds staging (one barrier per K-step;
//    next tile's DMA issued right after the barrier, hides under compute).
//  * XCD-chunked block swizzle: each XCD owns 8 consecutive m0 tiles x all 24
//    column-blocks -> the shared 2 MB x-slab stays in that XCD's L2.
// Q/K output [bh][t][d] via LDS-transpose epilogue; V output [bh][d][t].
// q pre-scaled by log2(e)/32.
// ---------------------------------------------------------------------------
__global__ __launch_bounds__(256) void k_qkv(
    const unsigned short* __restrict__ x,   // [8192][1024] bf16
    const unsigned short* __restrict__ wq,  // [3072][1024] bf16
    unsigned short* __restrict__ qb,        // [64 bh][2048 t][64 d]
    unsigned short* __restrict__ kb,        // [64 bh][2048 t][64 d]
    unsigned short* __restrict__ vb)        // [64 bh][64 d][2048 t]
{
    // [buf][A|B]: A at +0 (4096 sh), B at +4096; buf stride 8192 sh.
    // Q/K epilogue reuses [0,9216) as T[128][72].
    __shared__ unsigned short SM[16384];

    const int tid  = threadIdx.x;
    const int wave = tid >> 6, lane = tid & 63;
    const int quad = lane >> 4, l16 = lane & 15;
    const int wm = wave >> 1, wn = wave & 1;

    // XCD-chunked swizzle: dispatch id fid -> xcd = fid&7 (round-robin);
    // give xcd a contiguous slab of 192 blocks = 8 m0-tiles x 24 col-blocks.
    const int fid  = blockIdx.y * 24 + blockIdx.x;
    const int nfid = (fid & 7) * 192 + (fid >> 3);
    const int bx = nfid % 24;
    const int m0 = (nfid / 24) * 128;
    const int kk = bx >> 3;
    const int cb = bx & 7;

    // staging: wave w covers rows w*32 .. w*32+31 in two 16-row chunks
    const int srow = lane >> 2;          // 0..15
    const int sc8  = (lane & 3) * 8;     // 0,8,16,24
    const int row0 = wave * 32 + srow;
    const int row1 = row0 + 16;
    int bn0, bn1;
    if (kk < 2) {
        // column n -> d = n&63, h = cb*2 + (n>>6)
        bn0 = (row0 & 63) * 48 + kk * 16 + cb * 2 + (row0 >> 6);
        bn1 = (row1 & 63) * 48 + kk * 16 + cb * 2 + (row1 >> 6);
    } else {
        // column n -> d = cb*8 + (n>>4), h = n&15
        bn0 = (cb * 8 + (row0 >> 4)) * 48 + 32 + (row0 & 15);
        bn1 = (cb * 8 + (row1 >> 4)) * 48 + 32 + (row1 & 15);
    }

    floatx4 acc[4][4];
#pragma unroll
    for (int i = 0; i < 4; i++)
#pragma unroll
        for (int j = 0; j < 4; j++) acc[i][j] = (floatx4){0.f, 0.f, 0.f, 0.f};

#define QKV_STAGE(BUF, K0)                                                        \
    do {                                                                          \
        GLD16(&x[(m0 + row0) * 1024 + (K0) + sc8],                                \
              &SM[(BUF) * 8192 + (wave * 32) * 32]);                              \
        GLD16(&x[(m0 + row1) * 1024 + (K0) + sc8],                                \
              &SM[(BUF) * 8192 + (wave * 32 + 16) * 32]);                         \
        GLD16(&wq[bn0 * 1024 + (K0) + sc8],                                       \
              &SM[(BUF) * 8192 + 4096 + (wave * 32) * 32]);                       \
        GLD16(&wq[bn1 * 1024 + (K0) + sc8],                                       \
              &SM[(BUF) * 8192 + 4096 + (wave * 32 + 16) * 32]);                  \
    } while (0)

    QKV_STAGE(0, 0);
    int buf = 0;
    for (int k0 = 0; k0 < 1024; k0 += 32) {
        __syncthreads();                    // stage(buf) done (vmcnt 0), prev compute done
        if (k0 + 32 < 1024) QKV_STAGE(buf ^ 1, k0 + 32);

        const unsigned short* Ab = &SM[buf * 8192];
        const unsigned short* Bb = &SM[buf * 8192 + 4096];
        short8 af[4], bfv[4];
#pragma unroll
        for (int mi = 0; mi < 4; mi++)
            af[mi] = *(const short8*)&Ab[(wm * 64 + mi * 16 + l16) * 32 + quad * 8];
#pragma unroll
        for (int ni = 0; ni < 4; ni++)
            bfv[ni] = *(const short8*)&Bb[(wn * 64 + ni * 16 + l16) * 32 + quad * 8];
#pragma unroll
        for (int mi = 0; mi < 4; mi++)
#pragma unroll
            for (int ni = 0; ni < 4; ni++)
                acc[mi][ni] = mfma16(af[mi], bfv[ni], acc[mi][ni]);
        buf ^= 1;
    }
    __syncthreads();   // all waves done with SM before epilogue reuse

    if (kk == 2) {
        // V epilogue: [bh][d][t], packed ushort4 along t
#pragma unroll
        for (int ni = 0; ni < 4; ni++) {
            const int d = cb * 8 + wn * 4 + ni;
#pragma unroll
            for (int mi = 0; mi < 4; mi++) {
                const int m  = m0 + wm * 64 + mi * 16 + quad * 4;
                const int b  = m >> 11;
                const int tt = m & 2047;
                ushort4 pk;
                pk.x = f2bf_bits(acc[mi][ni][0]);
                pk.y = f2bf_bits(acc[mi][ni][1]);
                pk.z = f2bf_bits(acc[mi][ni][2]);
                pk.w = f2bf_bits(acc[mi][ni][3]);
                *(ushort4*)&vb[((b * 16 + l16) * 64 + d) * 2048 + tt] = pk;
            }
        }
    } else {
        // Q/K epilogue: LDS transpose to [bh][t][d], one h-slab per pass.
        const float scale = (kk == 0) ? 0.045084220027780106f : 1.0f;  // log2(e)/32
        unsigned short* dst = (kk == 0) ? qb : kb;
        const int b = m0 >> 11, tt0 = m0 & 2047;   // block lies in one batch
#pragma unroll
        for (int s = 0; s < 2; s++) {
            if (wn == s) {  // waves s and s+2 own this h-slab (wm = 0,1)
#pragma unroll
                for (int ni = 0; ni < 4; ni++) {
                    const int d = ni * 16 + l16;
#pragma unroll
                    for (int mi = 0; mi < 4; mi++) {
                        const int tl = wm * 64 + mi * 16 + quad * 4;
#pragma unroll
                        for (int r = 0; r < 4; r++)
                            SM[(tl + r) * 72 + d] = f2bf_bits(acc[mi][ni][r] * scale);
                    }
                }
            }
            __syncthreads();
            // coalesced read-back: full 128B t-rows
#pragma unroll
            for (int u = 0; u < 4; u++) {
                const int w  = tid + u * 256;     // 0..1023
                const int tl = w >> 3;
                const int ch = (w & 7) * 8;
                *(uint4*)&dst[((b * 16 + cb * 2 + s) * 2048 + tt0 + tl) * 64 + ch] =
                    *(const uint4*)&SM[tl * 72 + ch];
            }
            __syncthreads();
        }
    }
#undef QKV_STAGE
}

// ---------------------------------------------------------------------------
// Kernel 2: flash attention — UNCHANGED from round 1 (KVBLK=128, T14 reg
// prefetch, setprio around MFMA).  Delta vs round-0 still unmeasured; will
// surface in top-5 counters once k_qkv drops.
// ---------------------------------------------------------------------------
__global__ __launch_bounds__(512) void k_attn(
    const unsigned short* __restrict__ qt,  // [64][2048][64]  (bh, t, d)
    const unsigned short* __restrict__ kt,  // [64][2048][64]
    const unsigned short* __restrict__ vg,  // [64][64][2048]  (bh, d, t)
    __hip_bfloat16* __restrict__ og)        // [4][2048][1024]
{
    __shared__ unsigned short Ks[128 * 72];     // [key][d]       18432 B
    __shared__ unsigned short Vt[64 * 136];     // [d][key]       17408 B
    __shared__ unsigned short Pt[8 * 32 * 72];  // [qrow][key]    36864 B

    const int tid  = threadIdx.x;
    const int wave = tid >> 6, lane = tid & 63;
    const int quad = lane >> 4, l16 = lane & 15;
    const int blk = blockIdx.x;
    const int bh  = (blk & 7) | ((blk >> 6) << 3);  // XCD-affine
    const int q0  = ((blk >> 3) & 7) * 256;
    const int qr  = q0 + wave * 32;

    short8 qf[2][2];
#pragma unroll
    for (int mi = 0; mi < 2; mi++)
#pragma unroll
        for (int ks = 0; ks < 2; ks++)
            qf[mi][ks] = *(const short8*)&qt[(bh * 2048 + qr + mi * 16 + l16) * 64 + ks * 32 + quad * 8];

    float lsum[2] = {0.f, 0.f};
    floatx4 o[2][4];
#pragma unroll
    for (int mi = 0; mi < 2; mi++)
#pragma unroll
        for (int di = 0; di < 4; di++) o[mi][di] = (floatx4){0.f, 0.f, 0.f, 0.f};

    const int kr = tid >> 3, kc = (tid & 7) * 8;    // K rows kr, kr+64
    const int vd = tid >> 4, vc = (tid & 15) * 8;   // V d-rows vd, vd+32

    uint4 rk0 = *(const uint4*)&kt[(bh * 2048 + kr) * 64 + kc];
    uint4 rk1 = *(const uint4*)&kt[(bh * 2048 + 64 + kr) * 64 + kc];
    uint4 rv0 = *(const uint4*)&vg[(bh * 64 + vd) * 2048 + vc];
    uint4 rv1 = *(const uint4*)&vg[(bh * 64 + 32 + vd) * 2048 + vc];

    for (int j0 = 0; j0 < 2048; j0 += 128) {
        *(uint4*)&Ks[kr * 72 + kc]         = rk0;
        *(uint4*)&Ks[(64 + kr) * 72 + kc]  = rk1;
        *(uint4*)&Vt[vd * 136 + vc]        = rv0;
        *(uint4*)&Vt[(32 + vd) * 136 + vc] = rv1;
        __syncthreads();
        if (j0 + 128 < 2048) {
            rk0 = *(const uint4*)&kt[(bh * 2048 + j0 + 128 + kr) * 64 + kc];
            rk1 = *(const uint4*)&kt[(bh * 2048 + j0 + 192 + kr) * 64 + kc];
            rv0 = *(const uint4*)&vg[(bh * 64 + vd) * 2048 + j0 + 128 + vc];
            rv1 = *(const uint4*)&vg[(bh * 64 + 32 + vd) * 2048 + j0 + 128 + vc];
        }

#pragma unroll
        for (int jj = 0; jj < 2; jj++) {
            const int kb0 = jj * 64;

            floatx4 st[2][4];
#pragma unroll
            for (int mi = 0; mi < 2; mi++)
#pragma unroll
                for (int nk = 0; nk < 4; nk++) st[mi][nk] = (floatx4){0.f, 0.f, 0.f, 0.f};
#pragma unroll
            for (int ks = 0; ks < 2; ks++) {
                short8 kf[4];
#pragma unroll
                for (int nk = 0; nk < 4; nk++)
                    kf[nk] = *(const short8*)&Ks[(kb0 + nk * 16 + l16) * 72 + ks * 32 + quad * 8];
                __builtin_amdgcn_s_setprio(1);
#pragma unroll
                for (int mi = 0; mi < 2; mi++)
#pragma unroll
                    for (int nk = 0; nk < 4; nk++)
                        st[mi][nk] = mfma16(kf[nk], qf[mi][ks], st[mi][nk]);
                __builtin_amdgcn_s_setprio(0);
            }

#pragma unroll
            for (int mi = 0; mi < 2; mi++) {
#pragma unroll
                for (int nk = 0; nk < 4; nk++) {
                    const float p0 = fast_exp2(st[mi][nk][0]);
                    const float p1 = fast_exp2(st[mi][nk][1]);
                    const float p2 = fast_exp2(st[mi][nk][2]);
                    const float p3 = fast_exp2(st[mi][nk][3]);
                    lsum[mi] += (p0 + p1) + (p2 + p3);
                    ushort4 pk;
                    pk.x = f2bf_bits(p0);
                    pk.y = f2bf_bits(p1);
                    pk.z = f2bf_bits(p2);
                    pk.w = f2bf_bits(p3);
                    *(ushort4*)&Pt[(wave * 32 + mi * 16 + l16) * 72 + nk * 16 + quad * 4] = pk;
                }
            }
            __builtin_amdgcn_s_waitcnt(0xc07f);  // lgkmcnt(0): wave-local LDS RAW

#pragma unroll
            for (int ks = 0; ks < 2; ks++) {
                short8 pf[2], vf[4];
#pragma unroll
                for (int mi = 0; mi < 2; mi++)
                    pf[mi] = *(const short8*)&Pt[(wave * 32 + mi * 16 + l16) * 72 + ks * 32 + quad * 8];
#pragma unroll
                for (int di = 0; di < 4; di++)
                    vf[di] = *(const short8*)&Vt[(di * 16 + l16) * 136 + kb0 + ks * 32 + quad * 8];
                __builtin_amdgcn_s_setprio(1);
#pragma unroll
                for (int mi = 0; mi < 2; mi++)
#pragma unroll
                    for (int di = 0; di < 4; di++)
                        o[mi][di] = mfma16(pf[mi], vf[di], o[mi][di]);
                __builtin_amdgcn_s_setprio(0);
            }
        }
        __syncthreads();
    }

#pragma unroll
    for (int mi = 0; mi < 2; mi++) {
        float t = lsum[mi];
        t += __shfl_xor(t, 16);
        t += __shfl_xor(t, 32);
        lsum[mi] = t;
    }

    const int b = bh >> 4, h = bh & 15;
#pragma unroll
    for (int mi = 0; mi < 2; mi++) {
#pragma unroll
        for (int r = 0; r < 4; r++) {
            const float inv = 1.0f / __shfl(lsum[mi], quad * 4 + r);
            const int t = qr + mi * 16 + quad * 4 + r;
#pragma unroll
            for (int di = 0; di < 4; di++)
                og[(b * 2048 + t) * 1024 + h * 64 + di * 16 + l16] =
                    __float2bfloat16(o[mi][di][r] * inv);
        }
    }
}

// ---------------------------------------------------------------------------
// Kernel 3: output projection.  Same dbuf staging + XCD-chunked swizzle.
// ---------------------------------------------------------------------------
__global__ __launch_bounds__(256) void k_out(
    const unsigned short* __restrict__ a,    // [8192][1024] bf16
    const unsigned short* __restrict__ wq,   // [1024][1024] bf16
    const float* __restrict__ bias,
    float* __restrict__ out)                 // [8192][1024] fp32
{
    __shared__ unsigned short SM[16384];

    const int tid  = threadIdx.x;
    const int wave = tid >> 6, lane = tid & 63;
    const int quad = lane >> 4, l16 = lane & 15;
    const int wm = wave >> 1, wn = wave & 1;

    // grid (8, 64): 512 blocks; xcd slab = 8 m0-tiles x all 8 col-blocks
    const int fid  = blockIdx.y * 8 + blockIdx.x;
    const int nfid = (fid & 7) * 64 + (fid >> 3);
    const int n0 = (nfid & 7) * 128;
    const int m0 = (nfid >> 3) * 128;

    const int srow = lane >> 2;
    const int sc8  = (lane & 3) * 8;
    const int row0 = wave * 32 + srow;
    const int row1 = row0 + 16;

    floatx4 acc[4][4];
#pragma unroll
    for (int i = 0; i < 4; i++)
#pragma unroll
        for (int j = 0; j < 4; j++) acc[i][j] = (floatx4){0.f, 0.f, 0.f, 0.f};

#define OUT_STAGE(BUF, K0)                                                        \
    do {                                                                          \
        GLD16(&a[(m0 + row0) * 1024 + (K0) + sc8],                                \
              &SM[(BUF) * 8192 + (wave * 32) * 32]);                              \
        GLD16(&a[(m0 + row1) * 1024 + (K0) + sc8],                                \
              &SM[(BUF) * 8192 + (wave * 32 + 16) * 32]);                         \
        GLD16(&wq[(n0 + row0) * 1024 + (K0) + sc8],                               \
              &SM[(BUF) * 8192 + 4096 + (wave * 32) * 32]);                       \
        GLD16(&wq[(n0 + row1) * 1024 + (K0) + sc8],                               \
              &SM[(BUF) * 8192 + 4096 + (wave * 32 + 16) * 32]);                  \
    } while (0)

    OUT_STAGE(0, 0);
    int buf = 0;
    for (int k0 = 0; k0 < 1024; k0 += 32) {
        __syncthreads();
        if (k0 + 32 < 1024) OUT_STAGE(buf ^ 1, k0 + 32);

        const unsigned short* Ab = &SM[buf * 8192];
        const unsigned short* Bb = &SM[buf * 8192 + 4096];
        short8 af[4], bfv[4];
#pragma unroll
        for (int mi = 0; mi < 4; mi++)
            af[mi] = *(const short8*)&Ab[(wm * 64 + mi * 16 + l16) * 32 + quad * 8];
#pragma unroll
        for (int ni = 0; ni < 4; ni++)
            bfv[ni] = *(const short8*)&Bb[(wn * 64 + ni * 16 + l16) * 32 + quad * 8];
#pragma unroll
        for (int mi = 0; mi < 4; mi++)
#pragma unroll
            for (int ni = 0; ni < 4; ni++)
                acc[mi][ni] = mfma16(af[mi], bfv[ni], acc[mi][ni]);
        buf ^= 1;
    }
#undef OUT_STAGE

#pragma unroll
    for (int ni = 0; ni < 4; ni++) {
        const int col = n0 + wn * 64 + ni * 16 + l16;
        const float bv = bias[col];
#pragma unroll
        for (int mi = 0; mi < 4; mi++) {
            const int mbase = m0 + wm * 64 + mi * 16 + quad * 4;
#pragma unroll
            for (int r = 0; r < 4; r++)
                out[(mbase + r) * 1024 + col] = acc[mi][ni][r] + bv;
        }
    }
}

// ---------------------------------------------------------------------------
extern "C" void kernel_launch(void* const* d_in, const int* in_sizes, int n_in,
                              void* d_out, int out_size, void* d_ws, size_t ws_size,
                              hipStream_t stream) {
    const float* x    = (const float*)d_in[0];
    const float* wqkv = (const float*)d_in[1];
    const float* wout = (const float*)d_in[2];
    const float* bout = (const float*)d_in[3];
    float* out = (float*)d_out;

    unsigned short* ws = (unsigned short*)d_ws;
    unsigned short* xb    = ws;                  // x bf16
    unsigned short* wqkvb = xb + 8388608;
    unsigned short* woutb = wqkvb + 3145728;
    unsigned short* qb    = woutb + 1048576;     // q [bh][t][d]
    unsigned short* kb    = qb + 8388608;        // k [bh][t][d]
    unsigned short* vb    = kb + 8388608;        // v [bh][d][t]
    unsigned short* ob    = vb + 8388608;        // attn out

    k_cvt<<<2048, 256, 0, stream>>>(x,    xb,    8388608 / 4);
    k_cvt<<<1024, 256, 0, stream>>>(wqkv, wqkvb, 3145728 / 4);
    k_cvt<<<512,  256, 0, stream>>>(wout, woutb, 1048576 / 4);

    k_qkv<<<dim3(24, 64), 256, 0, stream>>>(xb, wqkvb, qb, kb, vb);
    k_attn<<<512, 512, 0, stream>>>(qb, kb, vb, (__hip_bfloat16*)ob);
    k_out<<<dim3(8, 64), 256, 0, stream>>>(ob, woutb, bout, out);
}

// Round 3
// 254.237 us; speedup vs baseline: 1.3481x; 1.0543x over previous
//
#include <hip/hip_runtime.h>
#include <hip/hip_bf16.h>

// Problem: B=4, T=2048, DIM=1024, H=16, DH=64.  fp32 in/out, bf16 MFMA inside.
// qkv col o = d*48 + kk*16 + h (d outermost, h innermost).

typedef __attribute__((ext_vector_type(8))) short short8;
typedef __attribute__((ext_vector_type(4))) float floatx4;
typedef __attribute__((ext_vector_type(16))) float floatx16;

static __device__ __forceinline__ floatx4 mfma16(short8 a, short8 b, floatx4 c) {
    return __builtin_amdgcn_mfma_f32_16x16x32_bf16(a, b, c, 0, 0, 0);
}
static __device__ __forceinline__ floatx16 mfma32(short8 a, short8 b, floatx16 c) {
    return __builtin_amdgcn_mfma_f32_32x32x16_bf16(a, b, c, 0, 0, 0);
}

static __device__ __forceinline__ unsigned short f2bf_bits(float f) {
    __hip_bfloat16 h = __float2bfloat16(f);
    return *reinterpret_cast<unsigned short*>(&h);
}

static __device__ __forceinline__ float fast_exp2(float x) {
#if __has_builtin(__builtin_amdgcn_exp2f)
    return __builtin_amdgcn_exp2f(x);
#else
    return exp2f(x);
#endif
}

// pack two f32 -> one u32 of 2 bf16 (lo in [15:0], hi in [31:16])
static __device__ __forceinline__ unsigned cvt_pk_bf16(float lo, float hi) {
    unsigned r;
    asm("v_cvt_pk_bf16_f32 %0, %1, %2" : "=v"(r) : "v"(lo), "v"(hi));
    return r;
}

// m214-verified idiom: swap(pk(p0,p1), pk(p4,p5)) -> both outputs usable.
static __device__ __forceinline__ void plane32_swap(unsigned& x, unsigned& y) {
#if __has_builtin(__builtin_amdgcn_permlane32_swap)
    typedef unsigned int uintx2 __attribute__((ext_vector_type(2)));
    uintx2 r = __builtin_amdgcn_permlane32_swap(x, y, false, false);
    x = r[0];
    y = r[1];
#else
    asm volatile("v_permlane32_swap_b32 %0, %1" : "+v"(x), "+v"(y));
#endif
}

// async global->LDS, 16 B per lane; LDS dest = wave-uniform base + lane*16
#define GLD16(gptr, ldsptr)                                                  \
    __builtin_amdgcn_global_load_lds(                                        \
        (const __attribute__((address_space(1))) void*)(gptr),               \
        (__attribute__((address_space(3))) void*)(ldsptr), 16, 0, 0)

// ---------------------------------------------------------------------------
// Kernel 0: fp32 -> bf16 conversion
// ---------------------------------------------------------------------------
__global__ __launch_bounds__(256) void k_cvt(
    const float* __restrict__ src, unsigned short* __restrict__ dst, int n4)
{
    typedef __attribute__((ext_vector_type(4))) unsigned short ushort4v;
    for (int i = blockIdx.x * blockDim.x + threadIdx.x; i < n4;
         i += gridDim.x * blockDim.x) {
        const float4 v = ((const float4*)src)[i];
        ushort4v o;
        o.x = f2bf_bits(v.x);
        o.y = f2bf_bits(v.y);
        o.z = f2bf_bits(v.z);
        o.w = f2bf_bits(v.w);
        ((ushort4v*)dst)[i] = o;
    }
}

// ---------------------------------------------------------------------------
// Kernel 1: QKV projection (unchanged from round 2 — verified).
// ---------------------------------------------------------------------------
__global__ __launch_bounds__(256) void k_qkv(
    const unsigned short* __restrict__ x,   // [8192][1024] bf16
    const unsigned short* __restrict__ wq,  // [3072][1024] bf16
    unsigned short* __restrict__ qb,        // [64 bh][2048 t][64 d]
    unsigned short* __restrict__ kb,        // [64 bh][2048 t][64 d]
    unsigned short* __restrict__ vb)        // [64 bh][64 d][2048 t]
{
    __shared__ unsigned short SM[16384];

    const int tid  = threadIdx.x;
    const int wave = tid >> 6, lane = tid & 63;
    const int quad = lane >> 4, l16 = lane & 15;
    const int wm = wave >> 1, wn = wave & 1;

    const int fid  = blockIdx.y * 24 + blockIdx.x;
    const int nfid = (fid & 7) * 192 + (fid >> 3);
    const int bx = nfid % 24;
    const int m0 = (nfid / 24) * 128;
    const int kk = bx >> 3;
    const int cb = bx & 7;

    const int srow = lane >> 2;          // 0..15
    const int sc8  = (lane & 3) * 8;     // 0,8,16,24
    const int row0 = wave * 32 + srow;
    const int row1 = row0 + 16;
    int bn0, bn1;
    if (kk < 2) {
        bn0 = (row0 & 63) * 48 + kk * 16 + cb * 2 + (row0 >> 6);
        bn1 = (row1 & 63) * 48 + kk * 16 + cb * 2 + (row1 >> 6);
    } else {
        bn0 = (cb * 8 + (row0 >> 4)) * 48 + 32 + (row0 & 15);
        bn1 = (cb * 8 + (row1 >> 4)) * 48 + 32 + (row1 & 15);
    }

    floatx4 acc[4][4];
#pragma unroll
    for (int i = 0; i < 4; i++)
#pragma unroll
        for (int j = 0; j < 4; j++) acc[i][j] = (floatx4){0.f, 0.f, 0.f, 0.f};

#define QKV_STAGE(BUF, K0)                                                        \
    do {                                                                          \
        GLD16(&x[(m0 + row0) * 1024 + (K0) + sc8],                                \
              &SM[(BUF) * 8192 + (wave * 32) * 32]);                              \
        GLD16(&x[(m0 + row1) * 1024 + (K0) + sc8],                                \
              &SM[(BUF) * 8192 + (wave * 32 + 16) * 32]);                         \
        GLD16(&wq[bn0 * 1024 + (K0) + sc8],                                       \
              &SM[(BUF) * 8192 + 4096 + (wave * 32) * 32]);                       \
        GLD16(&wq[bn1 * 1024 + (K0) + sc8],                                       \
              &SM[(BUF) * 8192 + 4096 + (wave * 32 + 16) * 32]);                  \
    } while (0)

    QKV_STAGE(0, 0);
    int buf = 0;
    for (int k0 = 0; k0 < 1024; k0 += 32) {
        __syncthreads();
        if (k0 + 32 < 1024) QKV_STAGE(buf ^ 1, k0 + 32);

        const unsigned short* Ab = &SM[buf * 8192];
        const unsigned short* Bb = &SM[buf * 8192 + 4096];
        short8 af[4], bfv[4];
#pragma unroll
        for (int mi = 0; mi < 4; mi++)
            af[mi] = *(const short8*)&Ab[(wm * 64 + mi * 16 + l16) * 32 + quad * 8];
#pragma unroll
        for (int ni = 0; ni < 4; ni++)
            bfv[ni] = *(const short8*)&Bb[(wn * 64 + ni * 16 + l16) * 32 + quad * 8];
#pragma unroll
        for (int mi = 0; mi < 4; mi++)
#pragma unroll
            for (int ni = 0; ni < 4; ni++)
                acc[mi][ni] = mfma16(af[mi], bfv[ni], acc[mi][ni]);
        buf ^= 1;
    }
    __syncthreads();

    if (kk == 2) {
#pragma unroll
        for (int ni = 0; ni < 4; ni++) {
            const int d = cb * 8 + wn * 4 + ni;
#pragma unroll
            for (int mi = 0; mi < 4; mi++) {
                const int m  = m0 + wm * 64 + mi * 16 + quad * 4;
                const int b  = m >> 11;
                const int tt = m & 2047;
                ushort4 pk;
                pk.x = f2bf_bits(acc[mi][ni][0]);
                pk.y = f2bf_bits(acc[mi][ni][1]);
                pk.z = f2bf_bits(acc[mi][ni][2]);
                pk.w = f2bf_bits(acc[mi][ni][3]);
                *(ushort4*)&vb[((b * 16 + l16) * 64 + d) * 2048 + tt] = pk;
            }
        }
    } else {
        const float scale = (kk == 0) ? 0.045084220027780106f : 1.0f;  // log2(e)/32
        unsigned short* dst = (kk == 0) ? qb : kb;
        const int b = m0 >> 11, tt0 = m0 & 2047;
#pragma unroll
        for (int s = 0; s < 2; s++) {
            if (wn == s) {
#pragma unroll
                for (int ni = 0; ni < 4; ni++) {
                    const int d = ni * 16 + l16;
#pragma unroll
                    for (int mi = 0; mi < 4; mi++) {
                        const int tl = wm * 64 + mi * 16 + quad * 4;
#pragma unroll
                        for (int r = 0; r < 4; r++)
                            SM[(tl + r) * 72 + d] = f2bf_bits(acc[mi][ni][r] * scale);
                    }
                }
            }
            __syncthreads();
#pragma unroll
            for (int u = 0; u < 4; u++) {
                const int w  = tid + u * 256;
                const int tl = w >> 3;
                const int ch = (w & 7) * 8;
                *(uint4*)&dst[((b * 16 + cb * 2 + s) * 2048 + tt0 + tl) * 64 + ch] =
                    *(const uint4*)&SM[tl * 72 + ch];
            }
            __syncthreads();
        }
    }
#undef QKV_STAGE
}

// ---------------------------------------------------------------------------
// Kernel 2: flash attention — REWRITTEN (m214/T12 structure, D=64):
//  * 32x32x16 MFMA; S^T = K·Q^T so C col = lane&31 = qrow (P row lane-local)
//  * softmax fully in-register; P -> PV A-frags via cvt_pk_bf16 + permlane32
//    (no P LDS round-trip, no lgkmcnt serialization)
//  * 4 waves x 64 qrows each (K-frags reused across 2 qrow-blocks)
//  * K/V 64-key tiles in LDS (stride 72), T14 reg-prefetch double-step
// Per 64-key tile per wave: 16 ds_read_b128 for 32 MFMAs (was ~28 LDS ops/32).
// ---------------------------------------------------------------------------
__global__ __launch_bounds__(256, 2) void k_attn(
    const unsigned short* __restrict__ qt,  // [64][2048][64]  (bh, t, d)
    const unsigned short* __restrict__ kt,  // [64][2048][64]
    const unsigned short* __restrict__ vg,  // [64][64][2048]  (bh, d, t)
    __hip_bfloat16* __restrict__ og)        // [4][2048][1024]
{
    __shared__ unsigned short Ks[64 * 72];  // [key][d]
    __shared__ unsigned short Vt[64 * 72];  // [d][key]

    const int tid  = threadIdx.x;
    const int wave = tid >> 6, lane = tid & 63;
    const int l31  = lane & 31, hi = lane >> 5;
    const int blk = blockIdx.x;
    const int bh  = (blk & 7) | ((blk >> 6) << 3);  // XCD-affine
    const int q0  = ((blk >> 3) & 7) * 256;
    const int qr  = q0 + wave * 64;

    // Q fragments (B operand [16 dk][32 qrow]: col=l31=qrow, k=hi*8+j)
    short8 qf[2][4];
#pragma unroll
    for (int qb2 = 0; qb2 < 2; qb2++)
#pragma unroll
        for (int ks = 0; ks < 4; ks++)
            qf[qb2][ks] = *(const short8*)
                &qt[(bh * 2048 + qr + qb2 * 32 + l31) * 64 + ks * 16 + hi * 8];

    float lsum[2] = {0.f, 0.f};
    floatx16 o[2][2];
#pragma unroll
    for (int qb2 = 0; qb2 < 2; qb2++)
#pragma unroll
        for (int db = 0; db < 2; db++)
#pragma unroll
            for (int r = 0; r < 16; r++) o[qb2][db][r] = 0.f;

    // staging: thread -> K/V row tid>>2 (0..63), shorts (tid&3)*16 (2 x uint4)
    const int sr = tid >> 2, sc = (tid & 3) * 16;

    uint4 rka = *(const uint4*)&kt[(bh * 2048 + sr) * 64 + sc];
    uint4 rkb = *(const uint4*)&kt[(bh * 2048 + sr) * 64 + sc + 8];
    uint4 rva = *(const uint4*)&vg[(bh * 64 + sr) * 2048 + sc];
    uint4 rvb = *(const uint4*)&vg[(bh * 64 + sr) * 2048 + sc + 8];

    for (int j0 = 0; j0 < 2048; j0 += 64) {
        *(uint4*)&Ks[sr * 72 + sc]     = rka;
        *(uint4*)&Ks[sr * 72 + sc + 8] = rkb;
        *(uint4*)&Vt[sr * 72 + sc]     = rva;
        *(uint4*)&Vt[sr * 72 + sc + 8] = rvb;
        __syncthreads();
        if (j0 + 64 < 2048) {  // prefetch next tile; consumed at next loop top
            rka = *(const uint4*)&kt[(bh * 2048 + j0 + 64 + sr) * 64 + sc];
            rkb = *(const uint4*)&kt[(bh * 2048 + j0 + 64 + sr) * 64 + sc + 8];
            rva = *(const uint4*)&vg[(bh * 64 + sr) * 2048 + j0 + 64 + sc];
            rvb = *(const uint4*)&vg[(bh * 64 + sr) * 2048 + j0 + 64 + sc + 8];
        }

#pragma unroll
        for (int kb2 = 0; kb2 < 2; kb2++) {   // 32-key blocks
            // K fragments (A operand [32 key][16 dk]: row=l31, k=hi*8+j)
            short8 kf[4];
#pragma unroll
            for (int ks = 0; ks < 4; ks++)
                kf[ks] = *(const short8*)
                    &Ks[(kb2 * 32 + l31) * 72 + ks * 16 + hi * 8];

            // S^T = K Q^T
            floatx16 st[2];
#pragma unroll
            for (int qb2 = 0; qb2 < 2; qb2++)
#pragma unroll
                for (int r = 0; r < 16; r++) st[qb2][r] = 0.f;
            __builtin_amdgcn_s_setprio(1);
#pragma unroll
            for (int ks = 0; ks < 4; ks++)
#pragma unroll
                for (int qb2 = 0; qb2 < 2; qb2++)
                    st[qb2] = mfma32(kf[ks], qf[qb2][ks], st[qb2]);
            __builtin_amdgcn_s_setprio(0);

            // softmax in-register; build PV A-frags via cvt_pk + permlane32
            short8 paf[2][2];
#pragma unroll
            for (int qb2 = 0; qb2 < 2; qb2++) {
                float p[16];
#pragma unroll
                for (int r = 0; r < 16; r++) p[r] = fast_exp2(st[qb2][r]);
                lsum[qb2] += ((p[0] + p[1]) + (p[2] + p[3])) +
                             ((p[4] + p[5]) + (p[6] + p[7])) +
                             ((p[8] + p[9]) + (p[10] + p[11])) +
                             ((p[12] + p[13]) + (p[14] + p[15]));
#pragma unroll
                for (int hf = 0; hf < 2; hf++) {
                    const int r0 = hf * 8;
                    unsigned c01 = cvt_pk_bf16(p[r0 + 0], p[r0 + 1]);
                    unsigned c23 = cvt_pk_bf16(p[r0 + 2], p[r0 + 3]);
                    unsigned c45 = cvt_pk_bf16(p[r0 + 4], p[r0 + 5]);
                    unsigned c67 = cvt_pk_bf16(p[r0 + 6], p[r0 + 7]);
                    plane32_swap(c01, c45);  // -> a0 (keys hi*8+0,1), a2 (+4,5)
                    plane32_swap(c23, c67);  // -> a1 (keys hi*8+2,3), a3 (+6,7)
                    uint4 t4 = {c01, c23, c45, c67};
                    paf[qb2][hf] = *reinterpret_cast<short8*>(&t4);
                }
            }

            // O += P V   (B operand V [16 key][32 d]: col=l31=d, k=hi*8+j)
            short8 vf[2][2];
#pragma unroll
            for (int db = 0; db < 2; db++)
#pragma unroll
                for (int hf = 0; hf < 2; hf++)
                    vf[db][hf] = *(const short8*)
                        &Vt[(db * 32 + l31) * 72 + kb2 * 32 + hf * 16 + hi * 8];
            __builtin_amdgcn_s_setprio(1);
#pragma unroll
            for (int qb2 = 0; qb2 < 2; qb2++)
#pragma unroll
                for (int db = 0; db < 2; db++)
#pragma unroll
                    for (int hf = 0; hf < 2; hf++)
                        o[qb2][db] = mfma32(paf[qb2][hf], vf[db][hf], o[qb2][db]);
            __builtin_amdgcn_s_setprio(0);
        }
        __syncthreads();
    }

    // each lane summed its hi-half keys; partner lane holds the complement
    lsum[0] += __shfl_xor(lsum[0], 32);
    lsum[1] += __shfl_xor(lsum[1], 32);

    // epilogue: o / l -> [b][t][h*64+d];  D layout: col=l31=d,
    // row(qrow) = (r&3) + 8*(r>>2) + 4*hi
    const int b = bh >> 4, h = bh & 15;
#pragma unroll
    for (int qb2 = 0; qb2 < 2; qb2++) {
#pragma unroll
        for (int r = 0; r < 16; r++) {
            const int qrl = (r & 3) + 8 * (r >> 2) + 4 * hi;
            const float inv = 1.0f / __shfl(lsum[qb2], qrl);
            const int t = qr + qb2 * 32 + qrl;
#pragma unroll
            for (int db = 0; db < 2; db++)
                og[(b * 2048 + t) * 1024 + h * 64 + db * 32 + l31] =
                    __float2bfloat16(o[qb2][db][r] * inv);
        }
    }
}

// ---------------------------------------------------------------------------
// Kernel 3: output projection (unchanged from round 2 — verified).
// ---------------------------------------------------------------------------
__global__ __launch_bounds__(256) void k_out(
    const unsigned short* __restrict__ a,    // [8192][1024] bf16
    const unsigned short* __restrict__ wq,   // [1024][1024] bf16
    const float* __restrict__ bias,
    float* __restrict__ out)                 // [8192][1024] fp32
{
    __shared__ unsigned short SM[16384];

    const int tid  = threadIdx.x;
    const int wave = tid >> 6, lane = tid & 63;
    const int quad = lane >> 4, l16 = lane & 15;
    const int wm = wave >> 1, wn = wave & 1;

    const int fid  = blockIdx.y * 8 + blockIdx.x;
    const int nfid = (fid & 7) * 64 + (fid >> 3);
    const int n0 = (nfid & 7) * 128;
    const int m0 = (nfid >> 3) * 128;

    const int srow = lane >> 2;
    const int sc8  = (lane & 3) * 8;
    const int row0 = wave * 32 + srow;
    const int row1 = row0 + 16;

    floatx4 acc[4][4];
#pragma unroll
    for (int i = 0; i < 4; i++)
#pragma unroll
        for (int j = 0; j < 4; j++) acc[i][j] = (floatx4){0.f, 0.f, 0.f, 0.f};

#define OUT_STAGE(BUF, K0)                                                        \
    do {                                                                          \
        GLD16(&a[(m0 + row0) * 1024 + (K0) + sc8],                                \
              &SM[(BUF) * 8192 + (wave * 32) * 32]);                              \
        GLD16(&a[(m0 + row1) * 1024 + (K0) + sc8],                                \
              &SM[(BUF) * 8192 + (wave * 32 + 16) * 32]);                         \
        GLD16(&wq[(n0 + row0) * 1024 + (K0) + sc8],                               \
              &SM[(BUF) * 8192 + 4096 + (wave * 32) * 32]);                       \
        GLD16(&wq[(n0 + row1) * 1024 + (K0) + sc8],                               \
              &SM[(BUF) * 8192 + 4096 + (wave * 32 + 16) * 32]);                  \
    } while (0)

    OUT_STAGE(0, 0);
    int buf = 0;
    for (int k0 = 0; k0 < 1024; k0 += 32) {
        __syncthreads();
        if (k0 + 32 < 1024) OUT_STAGE(buf ^ 1, k0 + 32);

        const unsigned short* Ab = &SM[buf * 8192];
        const unsigned short* Bb = &SM[buf * 8192 + 4096];
        short8 af[4], bfv[4];
#pragma unroll
        for (int mi = 0; mi < 4; mi++)
            af[mi] = *(const short8*)&Ab[(wm * 64 + mi * 16 + l16) * 32 + quad * 8];
#pragma unroll
        for (int ni = 0; ni < 4; ni++)
            bfv[ni] = *(const short8*)&Bb[(wn * 64 + ni * 16 + l16) * 32 + quad * 8];
#pragma unroll
        for (int mi = 0; mi < 4; mi++)
#pragma unroll
            for (int ni = 0; ni < 4; ni++)
                acc[mi][ni] = mfma16(af[mi], bfv[ni], acc[mi][ni]);
        buf ^= 1;
    }
#undef OUT_STAGE

#pragma unroll
    for (int ni = 0; ni < 4; ni++) {
        const int col = n0 + wn * 64 + ni * 16 + l16;
        const float bv = bias[col];
#pragma unroll
        for (int mi = 0; mi < 4; mi++) {
            const int mbase = m0 + wm * 64 + mi * 16 + quad * 4;
#pragma unroll
            for (int r = 0; r < 4; r++)
                out[(mbase + r) * 1024 + col] = acc[mi][ni][r] + bv;
        }
    }
}

// ---------------------------------------------------------------------------
extern "C" void kernel_launch(void* const* d_in, const int* in_sizes, int n_in,
                              void* d_out, int out_size, void* d_ws, size_t ws_size,
                              hipStream_t stream) {
    const float* x    = (const float*)d_in[0];
    const float* wqkv = (const float*)d_in[1];
    const float* wout = (const float*)d_in[2];
    const float* bout = (const float*)d_in[3];
    float* out = (float*)d_out;

    unsigned short* ws = (unsigned short*)d_ws;
    unsigned short* xb    = ws;                  // x bf16
    unsigned short* wqkvb = xb + 8388608;
    unsigned short* woutb = wqkvb + 3145728;
    unsigned short* qb    = woutb + 1048576;     // q [bh][t][d]
    unsigned short* kb    = qb + 8388608;        // k [bh][t][d]
    unsigned short* vb    = kb + 8388608;        // v [bh][d][t]
    unsigned short* ob    = vb + 8388608;        // attn out

    k_cvt<<<2048, 256, 0, stream>>>(x,    xb,    8388608 / 4);
    k_cvt<<<1024, 256, 0, stream>>>(wqkv, wqkvb, 3145728 / 4);
    k_cvt<<<512,  256, 0, stream>>>(wout, woutb, 1048576 / 4);

    k_qkv<<<dim3(24, 64), 256, 0, stream>>>(xb, wqkvb, qb, kb, vb);
    k_attn<<<512, 256, 0, stream>>>(qb, kb, vb, (__hip_bfloat16*)ob);
    k_out<<<dim3(8, 64), 256, 0, stream>>>(ob, woutb, bout, out);
}